// Round 6
// baseline (210.654 us; speedup 1.0000x reference)
//
#include <hip/hip_runtime.h>
#include <hip/hip_bf16.h>

typedef __attribute__((ext_vector_type(8))) short bf16x8;
typedef __attribute__((ext_vector_type(4))) float f32x4;

#define Bc 2
#define Cc 64
#define Hc 128
#define Wc 128
#define Oc 64
#define NOFF 27
#define HWc (Hc * Wc)   // 16384
#define MAGIC 0x13579BDF

__device__ __forceinline__ short f2bf(float f) {
    __hip_bfloat16 h = __float2bfloat16(f);
    return __builtin_bit_cast(short, h);
}
__device__ __forceinline__ float bf2f(short s) {
    __hip_bfloat16 h = __builtin_bit_cast(__hip_bfloat16, s);
    return __bfloat162float(h);
}

__device__ __forceinline__ void spin_on(volatile int* f) {
    while (__hip_atomic_load((const int*)f, __ATOMIC_RELAXED, __HIP_MEMORY_SCOPE_AGENT) != MAGIC) {}
}
__device__ __forceinline__ void publish(int* f) {
    __hip_atomic_store(f, MAGIC, __ATOMIC_RELAXED, __HIP_MEMORY_SCOPE_AGENT);
}

// ---------------------------------------------------------------------------
// Single mega-kernel: transpose + weight-pack + offsets GEMM + bilinear +
// main GEMM, ordered by write-once magic flags (ws poison 0xAA != MAGIC, so
// no flag init needed; identical data is rewritten every launch, so even a
// stale-MAGIC read is benign).
// grid = 512 blocks x 256 thr; __launch_bounds__(256,2) guarantees >=2
// blocks/CU -> all 512 co-resident -> flag spins cannot deadlock.
// ---------------------------------------------------------------------------
__global__ __launch_bounds__(256, 2) void mega_dcn_kernel(
    const float* __restrict__ x, const float* __restrict__ w, const float* __restrict__ ow,
    const float* __restrict__ bias, const float* __restrict__ obias,
    short* __restrict__ xT, short* __restrict__ Ahi, short* __restrict__ Alo,
    short* __restrict__ Ohi, short* __restrict__ Olo,
    int* __restrict__ xflag, int* __restrict__ pflag,
    float* __restrict__ out) {
    int bid = blockIdx.x;
    int b = bid >> 8, rem = bid & 255;
    int h = rem >> 1, w0 = (rem & 1) << 6;
    int tid = threadIdx.x;
    int lane = tid & 63, wv = tid >> 6;
    int n_loc = lane & 15, quad = lane >> 4;
    int p_glob = wv * 16 + n_loc;
    int wpix = w0 + p_glob;
    int cb0 = quad * 8, cb1 = 32 + quad * 8;

    __shared__ float tile[64][68];     // 17.4 KB (phase A)
    __shared__ float4 wgt[576];        // 9.2 KB
    __shared__ int4   sidx[576];       // 9.2 KB
    __shared__ float  tmp[NOFF * 64];  // 6.9 KB
    __shared__ int    rowmin, rowmax;

    // =================== Phase A: produce xT tile + pack unit ===============
    bool packO = (bid >= 144 && bid < 216);
    // O-pack blocks pack FIRST (stage-1 blocker for every block)
    if (packO) {
        int idx = bid * 256 + tid;
        int t2 = idx - 144 * 256;
        int j = t2 & 7, ln = (t2 >> 3) & 63, ks = (t2 >> 9) % 18, mt = t2 / 9216;
        int o = mt * 16 + (ln & 15);
        int kk = ks >> 1;
        int c = (ks & 1) * 32 + (ln >> 4) * 8 + j;
        float v = (o < NOFF) ? ow[(o * Cc + c) * 9 + kk] : 0.f;
        short hi = f2bf(v);
        Ohi[t2] = hi; Olo[t2] = f2bf(v - bf2f(hi));
        __syncthreads();
        if (tid == 0) { __threadfence(); publish(&pflag[bid]); }
    }
    {   // transpose own (b,h,w0) half-row NCHW f32 -> NHWC bf16
        int c = tid >> 2, sub = tid & 3;
        const float* src = x + ((size_t)(b * Cc + c) * Hc + h) * Wc + w0 + sub * 16;
#pragma unroll
        for (int j = 0; j < 4; ++j)
            *(float4*)&tile[c][sub * 16 + 4 * j] = *(const float4*)(src + 4 * j);
        __syncthreads();
        int ww = tid >> 2, cs = (tid & 3) << 4;
        short* dst = xT + (((size_t)(b * Hc + h)) * Wc + w0 + ww) * Cc + cs;
        bf16x8 v0, v1;
#pragma unroll
        for (int j = 0; j < 8; ++j) {
            v0[j] = f2bf(tile[cs + j][ww]);
            v1[j] = f2bf(tile[cs + 8 + j][ww]);
        }
        *(bf16x8*)(dst) = v0;
        *(bf16x8*)(dst + 8) = v1;
        __syncthreads();
        if (tid == 0) { __threadfence(); publish(&xflag[bid]); }
    }
    if (bid < 144) {   // A-pack unit
        int idx = bid * 256 + tid;
        int j = idx & 7, ln = (idx >> 3) & 63, ks = (idx >> 9) % 18, mt = idx / 9216;
        int o = mt * 16 + (ln & 15);
        int kk = ks >> 1;
        int c = (ks & 1) * 32 + (ln >> 4) * 8 + j;
        float v = w[(o * Cc + c) * 9 + kk];
        short hi = f2bf(v);
        Ahi[idx] = hi; Alo[idx] = f2bf(v - bf2f(hi));
        __syncthreads();
        if (tid == 0) { __threadfence(); publish(&pflag[bid]); }
    }

    // =================== Wait 1: O-pack + own 3 input rows ==================
    {
        if (tid < 72) spin_on(&pflag[144 + tid]);
        else if (tid < 78) {
            int rsel = (tid - 72) >> 1;
            int row = min(max(h - 1 + rsel, 0), Hc - 1);
            spin_on(&xflag[b * 256 + row * 2 + ((tid - 72) & 1)]);
        }
        __threadfence();
        __syncthreads();
    }

    const short* xb = xT + (size_t)b * HWc * Cc;

    // =================== Stage 1: offsets GEMM (barrier-free) ===============
    f32x4 oacc0 = {0.f, 0.f, 0.f, 0.f}, oacc1 = {0.f, 0.f, 0.f, 0.f};
    bf16x8 s1A[2], s1B[2];
    {
        int yc = min(max(h - 1, 0), Hc - 1);
        int xc = min(max(wpix - 1, 0), Wc - 1);
        const short* base = xb + ((size_t)yc * Wc + xc) * Cc;
        s1A[0] = *(const bf16x8*)(base + cb0);
        s1A[1] = *(const bf16x8*)(base + cb1);
    }
#pragma unroll
    for (int kk = 0; kk < 9; ++kk) {
        bf16x8* cur = (kk & 1) ? s1B : s1A;
        bf16x8* nxt = (kk & 1) ? s1A : s1B;
        if (kk < 8) {
            int kk2 = kk + 1;
            int yc = min(max(h + kk2 / 3 - 1, 0), Hc - 1);
            int xc = min(max(wpix + kk2 % 3 - 1, 0), Wc - 1);
            const short* base = xb + ((size_t)yc * Wc + xc) * Cc;
            nxt[0] = *(const bf16x8*)(base + cb0);
            nxt[1] = *(const bf16x8*)(base + cb1);
        }
        int y = h + kk / 3 - 1, xw = wpix + kk % 3 - 1;
        bool val = ((unsigned)y < (unsigned)Hc) && ((unsigned)xw < (unsigned)Wc);
        bf16x8 z = {0, 0, 0, 0, 0, 0, 0, 0};
        bf16x8 b0 = val ? cur[0] : z;
        bf16x8 b1 = val ? cur[1] : z;
#pragma unroll
        for (int ks = 0; ks < 2; ++ks) {
            bf16x8 bf = ks ? b1 : b0;
            int ksg = kk * 2 + ks;
            bf16x8 ah0 = *(const bf16x8*)(Ohi + ((0 * 18 + ksg) * 64 + lane) * 8);
            bf16x8 al0 = *(const bf16x8*)(Olo + ((0 * 18 + ksg) * 64 + lane) * 8);
            oacc0 = __builtin_amdgcn_mfma_f32_16x16x32_bf16(ah0, bf, oacc0, 0, 0, 0);
            oacc0 = __builtin_amdgcn_mfma_f32_16x16x32_bf16(al0, bf, oacc0, 0, 0, 0);
            bf16x8 ah1 = *(const bf16x8*)(Ohi + ((1 * 18 + ksg) * 64 + lane) * 8);
            bf16x8 al1 = *(const bf16x8*)(Olo + ((1 * 18 + ksg) * 64 + lane) * 8);
            oacc1 = __builtin_amdgcn_mfma_f32_16x16x32_bf16(ah1, bf, oacc1, 0, 0, 0);
            oacc1 = __builtin_amdgcn_mfma_f32_16x16x32_bf16(al1, bf, oacc1, 0, 0, 0);
        }
    }
    {
        int mrow = quad * 4;
#pragma unroll
        for (int r = 0; r < 4; ++r) {
            int oc = mrow + r;
            if (oc < NOFF) tmp[oc * 64 + p_glob] = oacc0[r] + obias[oc];
            int oc2 = 16 + mrow + r;
            if (oc2 < NOFF) tmp[oc2 * 64 + p_glob] = oacc1[r] + obias[oc2];
        }
        if (tid == 0) { rowmin = Hc - 1; rowmax = 0; }
    }
    __syncthreads();

    // =================== bilinear table (+ row-range reduce) ================
    for (int t = tid; t < 576; t += 256) {
        int k = t >> 6, p = t & 63;
        float dy = tmp[k * 64 + p];
        float dx = tmp[(9 + k) * 64 + p];
        float mm = tmp[(18 + k) * 64 + p];
        float m  = 1.f / (1.f + __expf(-mm));
        float py = (float)(h - 1 + k / 3) + dy;
        float px = (float)(w0 + p - 1 + k % 3) + dx;
        float y0f = floorf(py), x0f = floorf(px);
        float fy = py - y0f, fx = px - x0f;
        int y0 = (int)y0f, x0i = (int)x0f;
        float vy0 = (y0 >= 0 && y0 < Hc) ? 1.f : 0.f;
        float vy1 = (y0 + 1 >= 0 && y0 + 1 < Hc) ? 1.f : 0.f;
        float vx0 = (x0i >= 0 && x0i < Wc) ? 1.f : 0.f;
        float vx1 = (x0i + 1 >= 0 && x0i + 1 < Wc) ? 1.f : 0.f;
        wgt[t] = make_float4((1.f - fy) * (1.f - fx) * m * vy0 * vx0,
                             (1.f - fy) * fx         * m * vy0 * vx1,
                             fy         * (1.f - fx) * m * vy1 * vx0,
                             fy         * fx         * m * vy1 * vx1);
        int r0 = min(max(y0, 0), Hc - 1);
        int r1 = min(max(y0 + 1, 0), Hc - 1);
        int cx0 = min(max(x0i, 0), Wc - 1);
        int cx1 = min(max(x0i + 1, 0), Wc - 1);
        sidx[t] = make_int4(r0 * Wc + cx0, r0 * Wc + cx1, r1 * Wc + cx0, r1 * Wc + cx1);
        atomicMin(&rowmin, r0);
        atomicMax(&rowmax, r1);
    }
    __syncthreads();

    // =================== Wait 2: A-pack + sampled row range =================
    {
        if (tid < 144) spin_on(&pflag[tid]);
        int mn = rowmin, cnt = (rowmax - rowmin + 1) * 2;
        if (tid < cnt)
            spin_on(&xflag[b * 256 + (mn + (tid >> 1)) * 2 + (tid & 1)]);
        __threadfence();
        __syncthreads();
    }

    // =================== Stage 2: main GEMM (barrier-free) ==================
    f32x4 acc[4] = {{0.f, 0.f, 0.f, 0.f}, {0.f, 0.f, 0.f, 0.f},
                    {0.f, 0.f, 0.f, 0.f}, {0.f, 0.f, 0.f, 0.f}};
    bf16x8 bufA[8], bufB[8];
    float4 w4 = wgt[p_glob];
    {
        int4 id = sidx[p_glob];
        const short* c00 = xb + (size_t)id.x * Cc;
        const short* c01 = xb + (size_t)id.y * Cc;
        const short* c10 = xb + (size_t)id.z * Cc;
        const short* c11 = xb + (size_t)id.w * Cc;
        bufA[0] = *(const bf16x8*)(c00 + cb0); bufA[1] = *(const bf16x8*)(c00 + cb1);
        bufA[2] = *(const bf16x8*)(c01 + cb0); bufA[3] = *(const bf16x8*)(c01 + cb1);
        bufA[4] = *(const bf16x8*)(c10 + cb0); bufA[5] = *(const bf16x8*)(c10 + cb1);
        bufA[6] = *(const bf16x8*)(c11 + cb0); bufA[7] = *(const bf16x8*)(c11 + cb1);
    }
#pragma unroll
    for (int kk = 0; kk < 9; ++kk) {
        bf16x8* cur = (kk & 1) ? bufB : bufA;
        bf16x8* nxt = (kk & 1) ? bufA : bufB;
        float4 w4n = w4;
        if (kk < 8) {
            int4 idn = sidx[(kk + 1) * 64 + p_glob];
            w4n = wgt[(kk + 1) * 64 + p_glob];
            const short* c00 = xb + (size_t)idn.x * Cc;
            const short* c01 = xb + (size_t)idn.y * Cc;
            const short* c10 = xb + (size_t)idn.z * Cc;
            const short* c11 = xb + (size_t)idn.w * Cc;
            nxt[0] = *(const bf16x8*)(c00 + cb0); nxt[1] = *(const bf16x8*)(c00 + cb1);
            nxt[2] = *(const bf16x8*)(c01 + cb0); nxt[3] = *(const bf16x8*)(c01 + cb1);
            nxt[4] = *(const bf16x8*)(c10 + cb0); nxt[5] = *(const bf16x8*)(c10 + cb1);
            nxt[6] = *(const bf16x8*)(c11 + cb0); nxt[7] = *(const bf16x8*)(c11 + cb1);
        }
        bf16x8 b0, b1;
#pragma unroll
        for (int j = 0; j < 8; ++j) {
            float s0 = w4.x * bf2f(cur[0][j]) + w4.y * bf2f(cur[2][j])
                     + w4.z * bf2f(cur[4][j]) + w4.w * bf2f(cur[6][j]);
            float s1 = w4.x * bf2f(cur[1][j]) + w4.y * bf2f(cur[3][j])
                     + w4.z * bf2f(cur[5][j]) + w4.w * bf2f(cur[7][j]);
            b0[j] = f2bf(s0);
            b1[j] = f2bf(s1);
        }
#pragma unroll
        for (int ks = 0; ks < 2; ++ks) {
            bf16x8 bf = ks ? b1 : b0;
            int ksg = kk * 2 + ks;
#pragma unroll
            for (int mt = 0; mt < 4; ++mt) {
                bf16x8 ah = *(const bf16x8*)(Ahi + ((mt * 18 + ksg) * 64 + lane) * 8);
                bf16x8 al = *(const bf16x8*)(Alo + ((mt * 18 + ksg) * 64 + lane) * 8);
                acc[mt] = __builtin_amdgcn_mfma_f32_16x16x32_bf16(ah, bf, acc[mt], 0, 0, 0);
                acc[mt] = __builtin_amdgcn_mfma_f32_16x16x32_bf16(al, bf, acc[mt], 0, 0, 0);
            }
        }
        w4 = w4n;
    }

    // =================== epilogue ===================
    int mrow = quad * 4;
    float* ob = out + ((size_t)b * Oc * Hc + h) * Wc + w0 + p_glob;
#pragma unroll
    for (int mt = 0; mt < 4; ++mt)
#pragma unroll
        for (int r = 0; r < 4; ++r) {
            int o = mt * 16 + mrow + r;
            ob[(size_t)o * HWc] = acc[mt][r] + bias[o];
        }
}

// ---------------------------------------------------------------------------
extern "C" void kernel_launch(void* const* d_in, const int* in_sizes, int n_in,
                              void* d_out, int out_size, void* d_ws, size_t ws_size,
                              hipStream_t stream) {
    const float* x        = (const float*)d_in[0];
    const float* weight   = (const float*)d_in[1];
    const float* bias     = (const float*)d_in[2];
    const float* offset_w = (const float*)d_in[3];
    const float* offset_b = (const float*)d_in[4];
    float* out = (float*)d_out;

    char* ws = (char*)d_ws;
    short* xT    = (short*)(ws + 0);            // 4,194,304 B (bf16 NHWC)
    short* Ahi   = (short*)(ws + 4194304);      // 73,728 B
    short* Alo   = (short*)(ws + 4268032);      // 73,728 B
    short* Ohi   = (short*)(ws + 4341760);      // 36,864 B
    short* Olo   = (short*)(ws + 4378624);      // 36,864 B
    int*   xflag = (int*)(ws + 4415488);        // 512 ints
    int*   pflag = (int*)(ws + 4417536);        // 216 ints (end 4,418,400)

    mega_dcn_kernel<<<Bc * Hc * 2, 256, 0, stream>>>(
        x, weight, offset_w, bias, offset_b,
        xT, Ahi, Alo, Ohi, Olo, xflag, pflag, out);
}

// Round 7
// 99.358 us; speedup vs baseline: 2.1202x; 2.1202x over previous
//
#include <hip/hip_runtime.h>
#include <hip/hip_bf16.h>

typedef __attribute__((ext_vector_type(8))) short bf16x8;
typedef __attribute__((ext_vector_type(4))) float f32x4;

#define Bc 2
#define Cc 64
#define Hc 128
#define Wc 128
#define Oc 64
#define NOFF 27
#define HWc (Hc * Wc)   // 16384

__device__ __forceinline__ short f2bf(float f) {
    __hip_bfloat16 h = __float2bfloat16(f);
    return __builtin_bit_cast(short, h);
}
__device__ __forceinline__ float bf2f(short s) {
    __hip_bfloat16 h = __builtin_bit_cast(__hip_bfloat16, s);
    return __bfloat162float(h);
}

// ---------------------------------------------------------------------------
// Kernel P: prep.
//  blocks 0..511:  transpose x NCHW f32 -> NHWC bf16 (one b,h,64px each)
//  blocks 512..727: pack weights (single bf16, no hi/lo split) into MFMA
//    A-frag layout. A[m=o][k]: lane L holds A[L&15][(L>>4)*8+j];
//    k = kk*64 + ks*32 + q*8 + j. Element ((mt*18+ksg)*64+lane)*8+j.
// ---------------------------------------------------------------------------
__global__ __launch_bounds__(256) void prep_kernel(
    const float* __restrict__ x, const float* __restrict__ w, const float* __restrict__ ow,
    short* __restrict__ xT, short* __restrict__ Ahi, short* __restrict__ Ohi) {
    int bid = blockIdx.x;
    int t = threadIdx.x;
    if (bid < 512) {
        int b = bid >> 8, rem = bid & 255;
        int h = rem >> 1, w0 = (rem & 1) << 6;
        __shared__ float tile[64][68];
        {
            int c = t >> 2, sub = t & 3;
            const float* src = x + ((size_t)(b * Cc + c) * Hc + h) * Wc + w0 + sub * 16;
#pragma unroll
            for (int j = 0; j < 4; ++j)
                *(float4*)&tile[c][sub * 16 + 4 * j] = *(const float4*)(src + 4 * j);
        }
        __syncthreads();
        {
            int ww = t >> 2, cs = (t & 3) << 4;
            short* dst = xT + (((size_t)(b * Hc + h)) * Wc + w0 + ww) * Cc + cs;
            bf16x8 v0, v1;
#pragma unroll
            for (int j = 0; j < 8; ++j) {
                v0[j] = f2bf(tile[cs + j][ww]);
                v1[j] = f2bf(tile[cs + 8 + j][ww]);
            }
            *(bf16x8*)(dst) = v0;
            *(bf16x8*)(dst + 8) = v1;
        }
    } else {
        int idx = (bid - 512) * 256 + t;
        const int NM = 4 * 18 * 64 * 8;   // 36864
        const int NO = 2 * 18 * 64 * 8;   // 18432
        if (idx < NM) {
            int j = idx & 7, lane = (idx >> 3) & 63, ks = (idx >> 9) % 18, mt = idx / 9216;
            int o  = mt * 16 + (lane & 15);
            int kk = ks >> 1;
            int c  = (ks & 1) * 32 + (lane >> 4) * 8 + j;
            Ahi[idx] = f2bf(w[(o * Cc + c) * 9 + kk]);
        } else if (idx < NM + NO) {
            int t2 = idx - NM;
            int j = t2 & 7, lane = (t2 >> 3) & 63, ks = (t2 >> 9) % 18, mt = t2 / 9216;
            int o  = mt * 16 + (lane & 15);
            int kk = ks >> 1;
            int c  = (ks & 1) * 32 + (lane >> 4) * 8 + j;
            Ohi[t2] = f2bf((o < NOFF) ? ow[(o * Cc + c) * 9 + kk] : 0.f);
        }
    }
}

// ---------------------------------------------------------------------------
// Kernel F: fused DCN, barrier-free K-loops, single-bf16 weights.
// Each wave owns 16 pixels (n = lane&15); each lane gathers its own
// B-fragment channels straight from bf16 NHWC global (no LDS B-tile).
// Main-GEMM A for mt=0,1 staged in LDS (copy overlapped with stage 1) to
// offload the vmem/L1 pipe; mt=2,3 read from global (L1-cached).
// ---------------------------------------------------------------------------
__global__ __launch_bounds__(256, 2) void fused_dcn_kernel(
    const short* __restrict__ xT,
    const short* __restrict__ Ahi, const short* __restrict__ Ohi,
    const float* __restrict__ bias, const float* __restrict__ obias,
    float* __restrict__ out) {
    int bid = blockIdx.x;
    int b = bid >> 8, rem = bid & 255;
    int h = rem >> 1, w0 = (rem & 1) << 6;
    int tid = threadIdx.x;
    int lane = tid & 63, wv = tid >> 6;
    int n_loc = lane & 15, quad = lane >> 4;
    int p_glob = wv * 16 + n_loc;
    int wpix = w0 + p_glob;
    int cb0 = quad * 8, cb1 = 32 + quad * 8;

    __shared__ __align__(16) short Asm[2 * 18 * 64 * 8];  // 36.9 KB: A mt=0,1
    __shared__ float4 wgt[576];        // 9.2 KB
    __shared__ int4   sidx[576];       // 9.2 KB
    __shared__ float  tmp[NOFF * 64];  // 6.9 KB   (total 62.2 KB)

    const short* xb = xT + (size_t)b * HWc * Cc;

    // ============ Stage 1: offsets GEMM (barrier-free, hi-only) ============
    f32x4 oacc0 = {0.f, 0.f, 0.f, 0.f}, oacc1 = {0.f, 0.f, 0.f, 0.f};
    bf16x8 s1A[2], s1B[2];
    {
        int yc = min(max(h - 1, 0), Hc - 1);
        int xc = min(max(wpix - 1, 0), Wc - 1);
        const short* base = xb + ((size_t)yc * Wc + xc) * Cc;
        s1A[0] = *(const bf16x8*)(base + cb0);
        s1A[1] = *(const bf16x8*)(base + cb1);
    }
#pragma unroll
    for (int kk = 0; kk < 9; ++kk) {
        bf16x8* cur = (kk & 1) ? s1B : s1A;
        bf16x8* nxt = (kk & 1) ? s1A : s1B;
        if (kk < 8) {   // prefetch next tap
            int kk2 = kk + 1;
            int yc = min(max(h + kk2 / 3 - 1, 0), Hc - 1);
            int xc = min(max(wpix + kk2 % 3 - 1, 0), Wc - 1);
            const short* base = xb + ((size_t)yc * Wc + xc) * Cc;
            nxt[0] = *(const bf16x8*)(base + cb0);
            nxt[1] = *(const bf16x8*)(base + cb1);
        }
        int y = h + kk / 3 - 1, xw = wpix + kk % 3 - 1;
        bool val = ((unsigned)y < (unsigned)Hc) && ((unsigned)xw < (unsigned)Wc);
        bf16x8 z = {0, 0, 0, 0, 0, 0, 0, 0};
        bf16x8 b0 = val ? cur[0] : z;
        bf16x8 b1 = val ? cur[1] : z;
#pragma unroll
        for (int ks = 0; ks < 2; ++ks) {
            bf16x8 bf = ks ? b1 : b0;
            int ksg = kk * 2 + ks;
            bf16x8 ah0 = *(const bf16x8*)(Ohi + ((0 * 18 + ksg) * 64 + lane) * 8);
            oacc0 = __builtin_amdgcn_mfma_f32_16x16x32_bf16(ah0, bf, oacc0, 0, 0, 0);
            bf16x8 ah1 = *(const bf16x8*)(Ohi + ((1 * 18 + ksg) * 64 + lane) * 8);
            oacc1 = __builtin_amdgcn_mfma_f32_16x16x32_bf16(ah1, bf, oacc1, 0, 0, 0);
        }
    }
    {   // offsets D-tile -> LDS tmp[ch][p]  (D: n=lane&15, m=quad*4+r)
        int mrow = quad * 4;
#pragma unroll
        for (int r = 0; r < 4; ++r) {
            int oc = mrow + r;
            if (oc < NOFF) tmp[oc * 64 + p_glob] = oacc0[r] + obias[oc];
            int oc2 = 16 + mrow + r;
            if (oc2 < NOFF) tmp[oc2 * 64 + p_glob] = oacc1[r] + obias[oc2];
        }
    }
    // stage A (mt=0,1) into LDS: 2304 bf16x8 vectors, 9 per thread
    for (int i = tid; i < 2304; i += 256)
        *((bf16x8*)Asm + i) = *((const bf16x8*)Ahi + i);
    __syncthreads();

    // ===================== bilinear table =====================
    for (int t = tid; t < 576; t += 256) {
        int k = t >> 6, p = t & 63;
        float dy = tmp[k * 64 + p];
        float dx = tmp[(9 + k) * 64 + p];
        float mm = tmp[(18 + k) * 64 + p];
        float m  = 1.f / (1.f + __expf(-mm));
        float py = (float)(h - 1 + k / 3) + dy;
        float px = (float)(w0 + p - 1 + k % 3) + dx;
        float y0f = floorf(py), x0f = floorf(px);
        float fy = py - y0f, fx = px - x0f;
        int y0 = (int)y0f, x0i = (int)x0f;
        float vy0 = (y0 >= 0 && y0 < Hc) ? 1.f : 0.f;
        float vy1 = (y0 + 1 >= 0 && y0 + 1 < Hc) ? 1.f : 0.f;
        float vx0 = (x0i >= 0 && x0i < Wc) ? 1.f : 0.f;
        float vx1 = (x0i + 1 >= 0 && x0i + 1 < Wc) ? 1.f : 0.f;
        wgt[t] = make_float4((1.f - fy) * (1.f - fx) * m * vy0 * vx0,
                             (1.f - fy) * fx         * m * vy0 * vx1,
                             fy         * (1.f - fx) * m * vy1 * vx0,
                             fy         * fx         * m * vy1 * vx1);
        int cy0 = min(max(y0, 0), Hc - 1) * Wc;
        int cy1 = min(max(y0 + 1, 0), Hc - 1) * Wc;
        int cx0 = min(max(x0i, 0), Wc - 1);
        int cx1 = min(max(x0i + 1, 0), Wc - 1);
        sidx[t] = make_int4(cy0 + cx0, cy0 + cx1, cy1 + cx0, cy1 + cx1);
    }
    __syncthreads();

    // ============ Stage 2: main GEMM (barrier-free, A from LDS+L1) =========
    f32x4 acc[4] = {{0.f, 0.f, 0.f, 0.f}, {0.f, 0.f, 0.f, 0.f},
                    {0.f, 0.f, 0.f, 0.f}, {0.f, 0.f, 0.f, 0.f}};
    bf16x8 bufA[8], bufB[8];
    float4 w4 = wgt[p_glob];
    {
        int4 id = sidx[p_glob];
        const short* c00 = xb + (size_t)id.x * Cc;
        const short* c01 = xb + (size_t)id.y * Cc;
        const short* c10 = xb + (size_t)id.z * Cc;
        const short* c11 = xb + (size_t)id.w * Cc;
        bufA[0] = *(const bf16x8*)(c00 + cb0); bufA[1] = *(const bf16x8*)(c00 + cb1);
        bufA[2] = *(const bf16x8*)(c01 + cb0); bufA[3] = *(const bf16x8*)(c01 + cb1);
        bufA[4] = *(const bf16x8*)(c10 + cb0); bufA[5] = *(const bf16x8*)(c10 + cb1);
        bufA[6] = *(const bf16x8*)(c11 + cb0); bufA[7] = *(const bf16x8*)(c11 + cb1);
    }
#pragma unroll
    for (int kk = 0; kk < 9; ++kk) {
        bf16x8* cur = (kk & 1) ? bufB : bufA;
        bf16x8* nxt = (kk & 1) ? bufA : bufB;
        float4 w4n = w4;
        if (kk < 8) {   // prefetch next tap (8 gathers)
            int4 idn = sidx[(kk + 1) * 64 + p_glob];
            w4n = wgt[(kk + 1) * 64 + p_glob];
            const short* c00 = xb + (size_t)idn.x * Cc;
            const short* c01 = xb + (size_t)idn.y * Cc;
            const short* c10 = xb + (size_t)idn.z * Cc;
            const short* c11 = xb + (size_t)idn.w * Cc;
            nxt[0] = *(const bf16x8*)(c00 + cb0); nxt[1] = *(const bf16x8*)(c00 + cb1);
            nxt[2] = *(const bf16x8*)(c01 + cb0); nxt[3] = *(const bf16x8*)(c01 + cb1);
            nxt[4] = *(const bf16x8*)(c10 + cb0); nxt[5] = *(const bf16x8*)(c10 + cb1);
            nxt[6] = *(const bf16x8*)(c11 + cb0); nxt[7] = *(const bf16x8*)(c11 + cb1);
        }
        // bilinear blend in fp32, repack to bf16 B-fragments
        bf16x8 b0, b1;
#pragma unroll
        for (int j = 0; j < 8; ++j) {
            float s0 = w4.x * bf2f(cur[0][j]) + w4.y * bf2f(cur[2][j])
                     + w4.z * bf2f(cur[4][j]) + w4.w * bf2f(cur[6][j]);
            float s1 = w4.x * bf2f(cur[1][j]) + w4.y * bf2f(cur[3][j])
                     + w4.z * bf2f(cur[5][j]) + w4.w * bf2f(cur[7][j]);
            b0[j] = f2bf(s0);
            b1[j] = f2bf(s1);
        }
#pragma unroll
        for (int ks = 0; ks < 2; ++ks) {
            bf16x8 bf = ks ? b1 : b0;
            int ksg = kk * 2 + ks;
            bf16x8 a0 = *(const bf16x8*)(Asm + ((0 * 18 + ksg) * 64 + lane) * 8);
            acc[0] = __builtin_amdgcn_mfma_f32_16x16x32_bf16(a0, bf, acc[0], 0, 0, 0);
            bf16x8 a1 = *(const bf16x8*)(Asm + ((1 * 18 + ksg) * 64 + lane) * 8);
            acc[1] = __builtin_amdgcn_mfma_f32_16x16x32_bf16(a1, bf, acc[1], 0, 0, 0);
            bf16x8 a2 = *(const bf16x8*)(Ahi + ((2 * 18 + ksg) * 64 + lane) * 8);
            acc[2] = __builtin_amdgcn_mfma_f32_16x16x32_bf16(a2, bf, acc[2], 0, 0, 0);
            bf16x8 a3 = *(const bf16x8*)(Ahi + ((3 * 18 + ksg) * 64 + lane) * 8);
            acc[3] = __builtin_amdgcn_mfma_f32_16x16x32_bf16(a3, bf, acc[3], 0, 0, 0);
        }
        w4 = w4n;
    }

    // ===================== epilogue =====================
    int mrow = quad * 4;
    float* ob = out + ((size_t)b * Oc * Hc + h) * Wc + w0 + p_glob;
#pragma unroll
    for (int mt = 0; mt < 4; ++mt)
#pragma unroll
        for (int r = 0; r < 4; ++r) {
            int o = mt * 16 + mrow + r;
            ob[(size_t)o * HWc] = acc[mt][r] + bias[o];
        }
}

// ---------------------------------------------------------------------------
extern "C" void kernel_launch(void* const* d_in, const int* in_sizes, int n_in,
                              void* d_out, int out_size, void* d_ws, size_t ws_size,
                              hipStream_t stream) {
    const float* x        = (const float*)d_in[0];
    const float* weight   = (const float*)d_in[1];
    const float* bias     = (const float*)d_in[2];
    const float* offset_w = (const float*)d_in[3];
    const float* offset_b = (const float*)d_in[4];
    float* out = (float*)d_out;

    char* ws = (char*)d_ws;
    short* xT  = (short*)(ws + 0);              // 4,194,304 B (bf16 NHWC)
    short* Ahi = (short*)(ws + 4194304);        // 73,728 B
    short* Ohi = (short*)(ws + 4268032);        // 36,864 B  (end 4,304,896)

    prep_kernel<<<512 + 216, 256, 0, stream>>>(x, weight, offset_w, xT, Ahi, Ohi);
    fused_dcn_kernel<<<Bc * Hc * 2, 256, 0, stream>>>(xT, Ahi, Ohi, bias, offset_b, out);
}